// Round 5
// baseline (214.812 us; speedup 1.0000x reference)
//
#include <hip/hip_runtime.h>
#include <hip/hip_cooperative_groups.h>

namespace cg = cooperative_groups;

#define DIM 6
#define NSEG 65535
#define CH 64             // segments per chunk (per wave)
#define WPB 4             // waves (=chunks) per fold block
#define NBLK 256          // fold blocks; NBLK*WPB*CH >= NSEG -> 256 partials

// Padded partial-signature layout (per chunk), stride in floats.
// 16B-aligned sections: L1@0(6), L2@8(36), L3@48(216), L4@264(1296)
#define PSTRIDE 1568
#define PL1 0
#define PL2 8
#define PL3 48
#define PL4 264
#define NGRP 259          // 1 + 6 + 36 + 216 output groups of 6

// ---------------- Chen pair-combine helpers (padded layout) -----------------
__device__ __forceinline__ void chen_vals(const float* __restrict__ A,
                                          const float* __restrict__ B,
                                          int g, float* v) {
    if (g == 0) {
#pragma unroll
        for (int d = 0; d < 6; ++d) v[d] = A[PL1 + d] + B[PL1 + d];
    } else if (g < 7) {
        int a = g - 1;
        float a1 = A[PL1 + a];
        const float* Ar = A + PL2 + a * 6;
        const float* Br = B + PL2 + a * 6;
#pragma unroll
        for (int d = 0; d < 6; ++d) v[d] = Ar[d] + Br[d] + a1 * B[PL1 + d];
    } else if (g < 43) {
        int ab = g - 7, a = ab / 6, b = ab - a * 6;
        float a2 = A[PL2 + ab], a1 = A[PL1 + a];
        const float* Ar = A + PL3 + ab * 6;
        const float* Br = B + PL3 + ab * 6;
        const float* B2r = B + PL2 + b * 6;
#pragma unroll
        for (int d = 0; d < 6; ++d)
            v[d] = Ar[d] + Br[d] + a2 * B[PL1 + d] + a1 * B2r[d];
    } else {
        int abc = g - 43, ab = abc / 6, cc = abc - ab * 6, a = abc / 36,
            bc = abc - a * 36;
        float a3 = A[PL3 + abc], a2 = A[PL2 + ab], a1 = A[PL1 + a];
        const float* Ar = A + PL4 + abc * 6;
        const float* Br = B + PL4 + abc * 6;
        const float* B2r = B + PL2 + cc * 6;
        const float* B3r = B + PL3 + bc * 6;
#pragma unroll
        for (int d = 0; d < 6; ++d)
            v[d] = Ar[d] + Br[d] + a3 * B[PL1 + d] + a2 * B2r[d] + a1 * B3r[d];
    }
}

__device__ __forceinline__ int grp_off_padded(int g) {
    if (g == 0) return PL1;
    if (g < 7) return PL2 + (g - 1) * 6;
    if (g < 43) return PL3 + (g - 7) * 6;
    return PL4 + (g - 43) * 6;
}
__device__ __forceinline__ int grp_off_flat(int g) {
    if (g == 0) return 0;
    if (g < 7) return 6 + (g - 1) * 6;
    if (g < 43) return 42 + (g - 7) * 6;
    return 258 + (g - 43) * 6;
}

// ---------------- radix-16 in-LDS Chen tree (16 staged partials -> 1) -------
// cur/nxt are LDS ping-pong buffers; cur initially holds 16 partials.
// flat_out: 1 -> write flat 1554-float output; 0 -> write padded partial.
__device__ __forceinline__ void tree16(float* cur, float* nxt, float* out,
                                       int flat_out, int out_blk, int t) {
    int np = 8;
    while (true) {
        for (int idx = t; idx < np * NGRP; idx += 256) {
            int p = idx / NGRP, g = idx - p * NGRP;
            float v[6];
            chen_vals(cur + (2 * p) * PSTRIDE, cur + (2 * p + 1) * PSTRIDE, g, v);
            if (np == 1) {
                if (flat_out) {
                    int off = grp_off_flat(g);
#pragma unroll
                    for (int d = 0; d < 6; ++d) out[off + d] = v[d];
                } else {
                    float* O = out + (size_t)out_blk * PSTRIDE;
                    int off = grp_off_padded(g);
#pragma unroll
                    for (int d = 0; d < 6; ++d) O[off + d] = v[d];
                }
            } else {
                float* o = nxt + p * PSTRIDE + grp_off_padded(g);
#pragma unroll
                for (int d = 0; d < 6; ++d) o[d] = v[d];
            }
        }
        if (np == 1) break;
        __syncthreads();
        float* tmp = cur; cur = nxt; nxt = tmp;
        np >>= 1;
    }
}

// ---------------- Single cooperative kernel: fold + combine + full tree -----
// Phase A (256 blocks): per-wave register Chen fold over CH=64 segs, in-block
//   radix-4 combine -> ws0[256 partials]   (proven round-4 code)
// Phase B (16 blocks): stage 16 partials coalesced -> LDS, radix-16 tree
//   -> ws1[16 partials]
// Phase C (block 0):  stage 16 -> LDS, radix-16 tree -> flat output
__global__ __launch_bounds__(256) void sig_all(const float* __restrict__ x,
                                               float* __restrict__ ws0,
                                               float* __restrict__ ws1,
                                               float* __restrict__ out) {
    __shared__ __align__(16) union SH {
        struct { float dxs[WPB * CH * 8]; float P[WPB * PSTRIDE];
                 float Q[2 * PSTRIDE]; } a;                 // 45.8 KB (fold)
        struct { float LIN[16 * PSTRIDE]; float W[8 * PSTRIDE]; } b; // 150.5 KB
    } sh;
    const int t = threadIdx.x;

    // ======================= Phase A: fold =================================
    {
        const int w = t >> 6;                 // wave id 0..3
        const int lane = t & 63;
        const int c = blockIdx.x * WPB + w;   // chunk id 0..1023
        const int j0 = c * CH;
        const int cnt = min(CH, NSEG - j0);   // 64, or 63 for the last chunk

        float* dxw = sh.a.dxs + w * (CH * 8);
        for (int f = lane; f < CH * 8; f += 64) dxw[f] = 0.f;
        __syncthreads();
        const float* xb = x + (size_t)j0 * DIM;
        for (int f = lane; f < cnt * DIM; f += 64) {
            int j = f / 6, k = f - j * 6;
            dxw[j * 8 + k] = xb[f + 6] - xb[f];
        }
        __syncthreads();

        const int ab = (lane < 36) ? lane : 35;
        const int a = ab / 6, b = ab - a * 6;
        const float* dxap = dxw + a;          // lane-varying LDS bases
        const float* dxbp = dxw + b;

        float r4[36], r3[6], r2 = 0.f, s1 = 0.f;
#pragma unroll
        for (int i = 0; i < 36; ++i) r4[i] = 0.f;
#pragma unroll
        for (int i = 0; i < 6; ++i) r3[i] = 0.f;

#pragma unroll 2
        for (int j = 0; j < CH; ++j) {
            const float4 q0 = *(const float4*)(dxw + j * 8);
            const float2 q1 = *(const float2*)(dxw + j * 8 + 4);
            const float dxv[6] = {q0.x, q0.y, q0.z, q0.w, q1.x, q1.y};
            const float dxa = dxap[j * 8];    // ds_read lane-addressed
            const float dxb = dxbp[j * 8];

            // t2 = S2 + dx_b*(S1/3 + dx_a/12)            (old S2, S1)
            float t2 = fmaf(dxb, fmaf(dxa, (1.f / 12.f), s1 * (1.f / 3.f)), r2);
            float t2h = 0.5f * t2;
            // S4[cd] += (S3[c] + t2*0.5*dx[c]) * dx[d]   (old S3)
            float wv[6];
#pragma unroll
            for (int cc = 0; cc < 6; ++cc) wv[cc] = fmaf(t2h, dxv[cc], r3[cc]);
#pragma unroll
            for (int cc = 0; cc < 6; ++cc)
#pragma unroll
                for (int d = 0; d < 6; ++d)
                    r4[cc * 6 + d] = fmaf(wv[cc], dxv[d], r4[cc * 6 + d]);
            // S3[c] += (S2 + t3*0.5*dx_b) * dx[c],  t3 = S1 + dx_a/3
            float t3 = fmaf(dxa, (1.f / 3.f), s1);
            float v = fmaf(0.5f * t3, dxb, r2);
#pragma unroll
            for (int cc = 0; cc < 6; ++cc) r3[cc] = fmaf(v, dxv[cc], r3[cc]);
            // S2 += (S1 + 0.5*dx_a) * dx_b ; S1 += dx_a
            r2 = fmaf(fmaf(0.5f, dxa, s1), dxb, r2);
            s1 += dxa;
        }

        // write wave partial into LDS (padded layout)
        if (lane < 36) {
            float* Pw = sh.a.P + w * PSTRIDE;
            if (a == b) Pw[PL1 + a] = s1;
            Pw[PL2 + ab] = r2;
            float* p3 = Pw + PL3 + ab * 6;
            *(float2*)(p3 + 0) = make_float2(r3[0], r3[1]);
            *(float2*)(p3 + 2) = make_float2(r3[2], r3[3]);
            *(float2*)(p3 + 4) = make_float2(r3[4], r3[5]);
            float* p4 = Pw + PL4 + ab * 36;
#pragma unroll
            for (int i = 0; i < 9; ++i)
                *(float4*)(p4 + 4 * i) = make_float4(r4[4 * i], r4[4 * i + 1],
                                                     r4[4 * i + 2], r4[4 * i + 3]);
        }
        __syncthreads();

        // level 1: (P0,P1)->Q0, (P2,P3)->Q1   (path order preserved)
        for (int idx = t; idx < 2 * NGRP; idx += 256) {
            int p = idx / NGRP, g = idx - p * NGRP;
            float v[6];
            chen_vals(sh.a.P + (2 * p) * PSTRIDE, sh.a.P + (2 * p + 1) * PSTRIDE,
                      g, v);
            float* o = sh.a.Q + p * PSTRIDE + grp_off_padded(g);
#pragma unroll
            for (int d = 0; d < 6; ++d) o[d] = v[d];
        }
        __syncthreads();

        // level 2: Q0*Q1 -> global partial for this block
        for (int idx = t; idx < NGRP; idx += 256) {
            float v[6];
            chen_vals(sh.a.Q, sh.a.Q + PSTRIDE, idx, v);
            float* O = ws0 + (size_t)blockIdx.x * PSTRIDE + grp_off_padded(idx);
#pragma unroll
            for (int d = 0; d < 6; ++d) O[d] = v[d];
        }
    }

    __threadfence();
    cg::this_grid().sync();

    // ======================= Phase B: 256 -> 16 ============================
    if (blockIdx.x < 16) {
        const float* gbase = ws0 + (size_t)blockIdx.x * 16 * PSTRIDE;
        const int nvec = 16 * (PSTRIDE / 4);
        for (int f = t; f < nvec; f += 256)
            *(float4*)(sh.b.LIN + 4 * f) = *(const float4*)(gbase + 4 * f);
        __syncthreads();
        tree16(sh.b.LIN, sh.b.W, ws1, 0, blockIdx.x, t);
    }

    __threadfence();
    cg::this_grid().sync();

    // ======================= Phase C: 16 -> 1 ==============================
    if (blockIdx.x == 0) {
        const int nvec = 16 * (PSTRIDE / 4);
        for (int f = t; f < nvec; f += 256)
            *(float4*)(sh.b.LIN + 4 * f) = *(const float4*)(ws1 + 4 * f);
        __syncthreads();
        tree16(sh.b.LIN, sh.b.W, out, 1, 0, t);
    }
}

// ---------------------------------------------------------------------------
extern "C" void kernel_launch(void* const* d_in, const int* in_sizes, int n_in,
                              void* d_out, int out_size, void* d_ws, size_t ws_size,
                              hipStream_t stream) {
    const float* x = (const float*)d_in[0];
    float* out = (float*)d_out;
    float* ws0 = (float*)d_ws;                          // 256 padded partials
    float* ws1 = ws0 + (size_t)NBLK * PSTRIDE;          // 16 padded partials

    void* args[] = {(void*)&x, (void*)&ws0, (void*)&ws1, (void*)&out};
    hipLaunchCooperativeKernel((void*)sig_all, dim3(NBLK), dim3(256), args, 0,
                               stream);
}

// Round 6
// 104.273 us; speedup vs baseline: 2.0601x; 2.0601x over previous
//
#include <hip/hip_runtime.h>

#define DIM 6
#define NSEG 65535
#define CH 64             // segments per chunk (per wave)
#define WPB 4             // waves (=chunks) per fold block
#define NBLK 256          // fold blocks; NBLK*WPB*CH >= NSEG -> 256 partials

// Padded partial-signature layout (per chunk), stride in floats.
// 16B-aligned sections: L1@0(6), L2@8(36), L3@48(216), L4@264(1296)
#define PSTRIDE 1568
#define PL1 0
#define PL2 8
#define PL3 48
#define PL4 264
#define NGRP 259          // 1 + 6 + 36 + 216 output groups of 6

// ---------------- Chen pair-combine helpers (padded layout) -----------------
// Group g: 0 -> L1; 1..6 -> L2 row a; 7..42 -> L3 row ab; 43..258 -> L4 row abc.
__device__ __forceinline__ void chen_vals(const float* __restrict__ A,
                                          const float* __restrict__ B,
                                          int g, float* v) {
    if (g == 0) {
#pragma unroll
        for (int d = 0; d < 6; ++d) v[d] = A[PL1 + d] + B[PL1 + d];
    } else if (g < 7) {
        int a = g - 1;
        float a1 = A[PL1 + a];
        const float* Ar = A + PL2 + a * 6;
        const float* Br = B + PL2 + a * 6;
#pragma unroll
        for (int d = 0; d < 6; ++d) v[d] = Ar[d] + Br[d] + a1 * B[PL1 + d];
    } else if (g < 43) {
        int ab = g - 7, a = ab / 6, b = ab - a * 6;
        float a2 = A[PL2 + ab], a1 = A[PL1 + a];
        const float* Ar = A + PL3 + ab * 6;
        const float* Br = B + PL3 + ab * 6;
        const float* B2r = B + PL2 + b * 6;
#pragma unroll
        for (int d = 0; d < 6; ++d)
            v[d] = Ar[d] + Br[d] + a2 * B[PL1 + d] + a1 * B2r[d];
    } else {
        int abc = g - 43, ab = abc / 6, cc = abc - ab * 6, a = abc / 36,
            bc = abc - a * 36;
        float a3 = A[PL3 + abc], a2 = A[PL2 + ab], a1 = A[PL1 + a];
        const float* Ar = A + PL4 + abc * 6;
        const float* Br = B + PL4 + abc * 6;
        const float* B2r = B + PL2 + cc * 6;
        const float* B3r = B + PL3 + bc * 6;
#pragma unroll
        for (int d = 0; d < 6; ++d)
            v[d] = Ar[d] + Br[d] + a3 * B[PL1 + d] + a2 * B2r[d] + a1 * B3r[d];
    }
}

__device__ __forceinline__ int grp_off_padded(int g) {
    if (g == 0) return PL1;
    if (g < 7) return PL2 + (g - 1) * 6;
    if (g < 43) return PL3 + (g - 7) * 6;
    return PL4 + (g - 43) * 6;
}
__device__ __forceinline__ int grp_off_flat(int g) {
    if (g == 0) return 0;
    if (g < 7) return 6 + (g - 1) * 6;
    if (g < 43) return 42 + (g - 7) * 6;
    return 258 + (g - 43) * 6;
}

// ---------------- Kernel 1: 4 waves/block, one 64-seg chunk per wave --------
// (UNCHANGED from the verified round-4 kernel.)  Each wave runs the
// register-resident Chen fold over CH=64 segments, writes its partial to LDS,
// then the block Chen-combines 4 partials -> 1 (radix-4, 2 levels) and writes
// ONE global partial.  256 blocks -> 256 partials (tree input 1.6 MB).
__global__ __launch_bounds__(256) void sig_fold4(const float* __restrict__ x,
                                                 float* __restrict__ part) {
    __shared__ __align__(16) float dxs[WPB * CH * 8];  // 8 KB
    __shared__ __align__(16) float P[WPB * PSTRIDE];   // 25.1 KB per-wave partials
    __shared__ __align__(16) float Q[2 * PSTRIDE];     // 12.5 KB combine buffer
    const int t = threadIdx.x;
    const int w = t >> 6;                 // wave id 0..3
    const int lane = t & 63;
    const int c = blockIdx.x * WPB + w;   // chunk id 0..1023
    const int j0 = c * CH;
    const int cnt = min(CH, NSEG - j0);   // 64, or 63 for the last chunk

    float* dxw = dxs + w * (CH * 8);
    for (int f = lane; f < CH * 8; f += 64) dxw[f] = 0.f;
    __syncthreads();
    const float* xb = x + (size_t)j0 * DIM;
    for (int f = lane; f < cnt * DIM; f += 64) {
        int j = f / 6, k = f - j * 6;
        dxw[j * 8 + k] = xb[f + 6] - xb[f];
    }
    __syncthreads();

    const int ab = (lane < 36) ? lane : 35;
    const int a = ab / 6, b = ab - a * 6;
    const float* dxap = dxw + a;          // lane-varying LDS bases
    const float* dxbp = dxw + b;

    float r4[36], r3[6], r2 = 0.f, s1 = 0.f;
#pragma unroll
    for (int i = 0; i < 36; ++i) r4[i] = 0.f;
#pragma unroll
    for (int i = 0; i < 6; ++i) r3[i] = 0.f;

#pragma unroll 2
    for (int j = 0; j < CH; ++j) {
        const float4 q0 = *(const float4*)(dxw + j * 8);
        const float2 q1 = *(const float2*)(dxw + j * 8 + 4);
        const float dxv[6] = {q0.x, q0.y, q0.z, q0.w, q1.x, q1.y}; // const-idx only
        const float dxa = dxap[j * 8];    // ds_read lane-addressed
        const float dxb = dxbp[j * 8];

        // t2 = S2 + dx_b*(S1/3 + dx_a/12)            (old S2, S1)
        float t2 = fmaf(dxb, fmaf(dxa, (1.f / 12.f), s1 * (1.f / 3.f)), r2);
        float t2h = 0.5f * t2;                        // *0.5 is exact
        // S4[cd] += (S3[c] + t2*0.5*dx[c]) * dx[d]   (old S3)
        float wv[6];
#pragma unroll
        for (int cc = 0; cc < 6; ++cc) wv[cc] = fmaf(t2h, dxv[cc], r3[cc]);
#pragma unroll
        for (int cc = 0; cc < 6; ++cc)
#pragma unroll
            for (int d = 0; d < 6; ++d)
                r4[cc * 6 + d] = fmaf(wv[cc], dxv[d], r4[cc * 6 + d]);
        // S3[c] += (S2 + t3*0.5*dx_b) * dx[c],  t3 = S1 + dx_a/3
        float t3 = fmaf(dxa, (1.f / 3.f), s1);
        float v = fmaf(0.5f * t3, dxb, r2);
#pragma unroll
        for (int cc = 0; cc < 6; ++cc) r3[cc] = fmaf(v, dxv[cc], r3[cc]);
        // S2 += (S1 + 0.5*dx_a) * dx_b ; S1 += dx_a
        r2 = fmaf(fmaf(0.5f, dxa, s1), dxb, r2);
        s1 += dxa;
    }

    // write wave partial into LDS (padded layout)
    if (lane < 36) {
        float* Pw = P + w * PSTRIDE;
        if (a == b) Pw[PL1 + a] = s1;
        Pw[PL2 + ab] = r2;
        float* p3 = Pw + PL3 + ab * 6;
        *(float2*)(p3 + 0) = make_float2(r3[0], r3[1]);
        *(float2*)(p3 + 2) = make_float2(r3[2], r3[3]);
        *(float2*)(p3 + 4) = make_float2(r3[4], r3[5]);
        float* p4 = Pw + PL4 + ab * 36;
#pragma unroll
        for (int i = 0; i < 9; ++i)
            *(float4*)(p4 + 4 * i) =
                make_float4(r4[4 * i], r4[4 * i + 1], r4[4 * i + 2], r4[4 * i + 3]);
    }
    __syncthreads();

    // level 1: (P0,P1)->Q0, (P2,P3)->Q1   (path order preserved)
    for (int idx = t; idx < 2 * NGRP; idx += 256) {
        int p = idx / NGRP, g = idx - p * NGRP;
        float v[6];
        chen_vals(P + (2 * p) * PSTRIDE, P + (2 * p + 1) * PSTRIDE, g, v);
        float* o = Q + p * PSTRIDE + grp_off_padded(g);
#pragma unroll
        for (int d = 0; d < 6; ++d) o[d] = v[d];
    }
    __syncthreads();

    // level 2: Q0*Q1 -> global partial for this block
    for (int idx = t; idx < NGRP; idx += 256) {
        float v[6];
        chen_vals(Q, Q + PSTRIDE, idx, v);
        float* O = part + (size_t)blockIdx.x * PSTRIDE + grp_off_padded(idx);
#pragma unroll
        for (int d = 0; d < 6; ++d) O[d] = v[d];
    }
}

// ---------------- Kernel 2: staged radix-16 in-block Chen tree --------------
// Stages 16 input partials into LDS with COALESCED float4 streams, then runs
// 4 Chen levels (8,4,2,1 pairs) out of LDS.  LDS = 150.5 KB (1 block/CU --
// irrelevant: only 16 or 1 blocks launched).  Same staged pattern verified in
// rounds 4 (sig_tree_s) and 5 (phases B/C).
__global__ __launch_bounds__(256) void sig_tree16(const float* __restrict__ in,
                                                  float* __restrict__ out,
                                                  int flat_out) {
    __shared__ __align__(16) float LIN[16 * PSTRIDE]; // 100.4 KB staged inputs
    __shared__ __align__(16) float W[8 * PSTRIDE];    // 50.2 KB ping-pong
    const int t = threadIdx.x;
    const float* gbase = in + (size_t)blockIdx.x * 16 * PSTRIDE;

    // coalesced staging: 16*PSTRIDE floats as float4 streams
    const int nvec = 16 * (PSTRIDE / 4);
    for (int f = t; f < nvec; f += 256)
        *(float4*)(LIN + 4 * f) = *(const float4*)(gbase + 4 * f);
    __syncthreads();

    float* cur = LIN;
    float* nxt = W;
    for (int np = 8;; np >>= 1) {
        for (int idx = t; idx < np * NGRP; idx += 256) {
            int p = idx / NGRP, g = idx - p * NGRP;
            float v[6];
            chen_vals(cur + (2 * p) * PSTRIDE, cur + (2 * p + 1) * PSTRIDE, g, v);
            if (np == 1) {
                if (flat_out) {
                    int off = grp_off_flat(g);
#pragma unroll
                    for (int d = 0; d < 6; ++d) out[off + d] = v[d];
                } else {
                    float* O = out + (size_t)blockIdx.x * PSTRIDE;
                    int off = grp_off_padded(g);
#pragma unroll
                    for (int d = 0; d < 6; ++d) O[off + d] = v[d];
                }
            } else {
                float* o = nxt + p * PSTRIDE + grp_off_padded(g);
#pragma unroll
                for (int d = 0; d < 6; ++d) o[d] = v[d];
            }
        }
        if (np == 1) break;
        __syncthreads();
        float* tmp = cur; cur = nxt; nxt = tmp;
    }
}

// ---------------------------------------------------------------------------
extern "C" void kernel_launch(void* const* d_in, const int* in_sizes, int n_in,
                              void* d_out, int out_size, void* d_ws, size_t ws_size,
                              hipStream_t stream) {
    const float* x = (const float*)d_in[0];
    float* out = (float*)d_out;
    float* ws0 = (float*)d_ws;                          // 256 padded partials
    float* ws1 = ws0 + (size_t)NBLK * PSTRIDE;          // 16 padded partials

    sig_fold4<<<NBLK, 256, 0, stream>>>(x, ws0);        // 65535 segs -> 256
    sig_tree16<<<16, 256, 0, stream>>>(ws0, ws1, 0);    // 256 -> 16
    sig_tree16<<<1, 256, 0, stream>>>(ws1, out, 1);     // 16  -> 1
}

// Round 7
// 97.640 us; speedup vs baseline: 2.2000x; 1.0679x over previous
//
#include <hip/hip_runtime.h>

#define DIM 6
#define NSEG 65535
#define CH 32             // segments per chunk (per wave)
#define WPB 4             // waves (=chunks) per fold block
#define NBLK 512          // fold blocks; NBLK*WPB*CH = 65536 >= NSEG -> 512 partials

// Padded partial-signature layout (per chunk), stride in floats.
// 16B-aligned sections: L1@0(6), L2@8(36), L3@48(216), L4@264(1296)
#define PSTRIDE 1568
#define PL1 0
#define PL2 8
#define PL3 48
#define PL4 264
#define NGRP 259          // 1 + 6 + 36 + 216 output groups of 6

// ---------------- Chen pair-combine helpers (padded layout) -----------------
// Group g: 0 -> L1; 1..6 -> L2 row a; 7..42 -> L3 row ab; 43..258 -> L4 row abc.
// A,B are padded 1568-float signatures (global or LDS via generic pointer).
__device__ __forceinline__ void chen_vals(const float* __restrict__ A,
                                          const float* __restrict__ B,
                                          int g, float* v) {
    if (g == 0) {
#pragma unroll
        for (int d = 0; d < 6; ++d) v[d] = A[PL1 + d] + B[PL1 + d];
    } else if (g < 7) {
        int a = g - 1;
        float a1 = A[PL1 + a];
        const float* Ar = A + PL2 + a * 6;
        const float* Br = B + PL2 + a * 6;
#pragma unroll
        for (int d = 0; d < 6; ++d) v[d] = Ar[d] + Br[d] + a1 * B[PL1 + d];
    } else if (g < 43) {
        int ab = g - 7, a = ab / 6, b = ab - a * 6;
        float a2 = A[PL2 + ab], a1 = A[PL1 + a];
        const float* Ar = A + PL3 + ab * 6;
        const float* Br = B + PL3 + ab * 6;
        const float* B2r = B + PL2 + b * 6;
#pragma unroll
        for (int d = 0; d < 6; ++d)
            v[d] = Ar[d] + Br[d] + a2 * B[PL1 + d] + a1 * B2r[d];
    } else {
        int abc = g - 43, ab = abc / 6, cc = abc - ab * 6, a = abc / 36,
            bc = abc - a * 36;
        float a3 = A[PL3 + abc], a2 = A[PL2 + ab], a1 = A[PL1 + a];
        const float* Ar = A + PL4 + abc * 6;
        const float* Br = B + PL4 + abc * 6;
        const float* B2r = B + PL2 + cc * 6;
        const float* B3r = B + PL3 + bc * 6;
#pragma unroll
        for (int d = 0; d < 6; ++d)
            v[d] = Ar[d] + Br[d] + a3 * B[PL1 + d] + a2 * B2r[d] + a1 * B3r[d];
    }
}

__device__ __forceinline__ int grp_off_padded(int g) {
    if (g == 0) return PL1;
    if (g < 7) return PL2 + (g - 1) * 6;
    if (g < 43) return PL3 + (g - 7) * 6;
    return PL4 + (g - 43) * 6;
}
__device__ __forceinline__ int grp_off_flat(int g) {
    if (g == 0) return 0;
    if (g < 7) return 6 + (g - 1) * 6;
    if (g < 43) return 42 + (g - 7) * 6;
    return 258 + (g - 43) * 6;
}

__device__ __forceinline__ void write_final(float* out, int flat_out, int g,
                                            const float* v, int blk) {
    if (flat_out) {
        int off = grp_off_flat(g);
#pragma unroll
        for (int d = 0; d < 6; ++d) out[off + d] = v[d];
    } else {
        float* O = out + (size_t)blk * PSTRIDE;
        int off = grp_off_padded(g);
#pragma unroll
        for (int d = 0; d < 6; ++d) O[off + d] = v[d];
    }
}

// ---------------- Kernel 1: 4 waves/block, one 32-seg chunk per wave --------
// Body identical to the verified round-4 fold; only CH (64->32) and NBLK
// (256->512) change: 512 blocks = 2 blocks/CU = 2 waves/SIMD, halving the
// serial per-wave chain and hiding LDS-read latency that 1 wave/SIMD exposed.
__global__ __launch_bounds__(256) void sig_fold4(const float* __restrict__ x,
                                                 float* __restrict__ part) {
    __shared__ __align__(16) float dxs[WPB * CH * 8];  // 4 KB
    __shared__ __align__(16) float P[WPB * PSTRIDE];   // 25.1 KB per-wave partials
    __shared__ __align__(16) float Q[2 * PSTRIDE];     // 12.5 KB combine buffer
    const int t = threadIdx.x;
    const int w = t >> 6;                 // wave id 0..3
    const int lane = t & 63;
    const int c = blockIdx.x * WPB + w;   // chunk id 0..2047
    const int j0 = c * CH;
    const int cnt = min(CH, NSEG - j0);   // 32, or 31 for the last chunk

    float* dxw = dxs + w * (CH * 8);
    for (int f = lane; f < CH * 8; f += 64) dxw[f] = 0.f;
    __syncthreads();
    const float* xb = x + (size_t)j0 * DIM;
    for (int f = lane; f < cnt * DIM; f += 64) {
        int j = f / 6, k = f - j * 6;
        dxw[j * 8 + k] = xb[f + 6] - xb[f];
    }
    __syncthreads();

    const int ab = (lane < 36) ? lane : 35;
    const int a = ab / 6, b = ab - a * 6;
    const float* dxap = dxw + a;          // lane-varying LDS bases
    const float* dxbp = dxw + b;

    float r4[36], r3[6], r2 = 0.f, s1 = 0.f;
#pragma unroll
    for (int i = 0; i < 36; ++i) r4[i] = 0.f;
#pragma unroll
    for (int i = 0; i < 6; ++i) r3[i] = 0.f;

#pragma unroll 2
    for (int j = 0; j < CH; ++j) {
        const float4 q0 = *(const float4*)(dxw + j * 8);
        const float2 q1 = *(const float2*)(dxw + j * 8 + 4);
        const float dxv[6] = {q0.x, q0.y, q0.z, q0.w, q1.x, q1.y}; // const-idx only
        const float dxa = dxap[j * 8];    // ds_read lane-addressed
        const float dxb = dxbp[j * 8];

        // t2 = S2 + dx_b*(S1/3 + dx_a/12)            (old S2, S1)
        float t2 = fmaf(dxb, fmaf(dxa, (1.f / 12.f), s1 * (1.f / 3.f)), r2);
        float t2h = 0.5f * t2;                        // *0.5 is exact
        // S4[cd] += (S3[c] + t2*0.5*dx[c]) * dx[d]   (old S3)
        float wv[6];
#pragma unroll
        for (int cc = 0; cc < 6; ++cc) wv[cc] = fmaf(t2h, dxv[cc], r3[cc]);
#pragma unroll
        for (int cc = 0; cc < 6; ++cc)
#pragma unroll
            for (int d = 0; d < 6; ++d)
                r4[cc * 6 + d] = fmaf(wv[cc], dxv[d], r4[cc * 6 + d]);
        // S3[c] += (S2 + t3*0.5*dx_b) * dx[c],  t3 = S1 + dx_a/3
        float t3 = fmaf(dxa, (1.f / 3.f), s1);
        float v = fmaf(0.5f * t3, dxb, r2);
#pragma unroll
        for (int cc = 0; cc < 6; ++cc) r3[cc] = fmaf(v, dxv[cc], r3[cc]);
        // S2 += (S1 + 0.5*dx_a) * dx_b ; S1 += dx_a
        r2 = fmaf(fmaf(0.5f, dxa, s1), dxb, r2);
        s1 += dxa;
    }

    // write wave partial into LDS (padded layout)
    if (lane < 36) {
        float* Pw = P + w * PSTRIDE;
        if (a == b) Pw[PL1 + a] = s1;
        Pw[PL2 + ab] = r2;
        float* p3 = Pw + PL3 + ab * 6;
        *(float2*)(p3 + 0) = make_float2(r3[0], r3[1]);
        *(float2*)(p3 + 2) = make_float2(r3[2], r3[3]);
        *(float2*)(p3 + 4) = make_float2(r3[4], r3[5]);
        float* p4 = Pw + PL4 + ab * 36;
#pragma unroll
        for (int i = 0; i < 9; ++i)
            *(float4*)(p4 + 4 * i) =
                make_float4(r4[4 * i], r4[4 * i + 1], r4[4 * i + 2], r4[4 * i + 3]);
    }
    __syncthreads();

    // level 1: (P0,P1)->Q0, (P2,P3)->Q1   (path order preserved)
    for (int idx = t; idx < 2 * NGRP; idx += 256) {
        int p = idx / NGRP, g = idx - p * NGRP;
        float v[6];
        chen_vals(P + (2 * p) * PSTRIDE, P + (2 * p + 1) * PSTRIDE, g, v);
        float* o = Q + p * PSTRIDE + grp_off_padded(g);
#pragma unroll
        for (int d = 0; d < 6; ++d) o[d] = v[d];
    }
    __syncthreads();

    // level 2: Q0*Q1 -> global partial for this block
    for (int idx = t; idx < NGRP; idx += 256) {
        float v[6];
        chen_vals(Q, Q + PSTRIDE, idx, v);
        float* O = part + (size_t)blockIdx.x * PSTRIDE + grp_off_padded(idx);
#pragma unroll
        for (int d = 0; d < 6; ++d) O[d] = v[d];
    }
}

// ---------------- Kernel 2: staged radix-(2*np0) in-block Chen tree ---------
// (UNCHANGED from the verified round-4 kernel.)  Stages gs = 2*np0 input
// partials into LDS with COALESCED float4 streams, then runs all Chen levels
// out of LDS.  np0 = 4.  LDS = 75.3 KB.
__global__ __launch_bounds__(256) void sig_tree_s(const float* __restrict__ in,
                                                  float* __restrict__ out,
                                                  int np0, int flat_out) {
    __shared__ __align__(16) float LIN[8 * PSTRIDE];  // 50.2 KB staged inputs
    __shared__ __align__(16) float W[4 * PSTRIDE];    // 25.1 KB ping-pong
    const int t = threadIdx.x;
    const int gs = np0 * 2;
    const float* gbase = in + (size_t)blockIdx.x * gs * PSTRIDE;

    // coalesced staging: gs*PSTRIDE floats as float4 streams
    const int nvec = gs * (PSTRIDE / 4);
    for (int f = t; f < nvec; f += 256)
        *(float4*)(LIN + 4 * f) = *(const float4*)(gbase + 4 * f);
    __syncthreads();

    float* cur = LIN;
    float* nxt = W;
    for (int np = np0;; np >>= 1) {
        for (int idx = t; idx < np * NGRP; idx += 256) {
            int p = idx / NGRP, g = idx - p * NGRP;
            float v[6];
            chen_vals(cur + (2 * p) * PSTRIDE, cur + (2 * p + 1) * PSTRIDE, g, v);
            if (np == 1) {
                write_final(out, flat_out, g, v, blockIdx.x);
            } else {
                float* o = nxt + p * PSTRIDE + grp_off_padded(g);
#pragma unroll
                for (int d = 0; d < 6; ++d) o[d] = v[d];
            }
        }
        if (np == 1) break;
        __syncthreads();
        float* tmp = cur; cur = nxt; nxt = tmp;
    }
}

// ---------------------------------------------------------------------------
extern "C" void kernel_launch(void* const* d_in, const int* in_sizes, int n_in,
                              void* d_out, int out_size, void* d_ws, size_t ws_size,
                              hipStream_t stream) {
    const float* x = (const float*)d_in[0];
    float* out = (float*)d_out;
    float* ws0 = (float*)d_ws;                          // 512 padded partials
    float* ws1 = ws0 + (size_t)NBLK * PSTRIDE;          // 64 padded partials
    float* ws2 = ws1 + (size_t)64 * PSTRIDE;            // 8 padded partials

    sig_fold4<<<NBLK, 256, 0, stream>>>(x, ws0);        // 65535 segs -> 512
    sig_tree_s<<<64, 256, 0, stream>>>(ws0, ws1, 4, 0); // 512 -> 64
    sig_tree_s<<<8, 256, 0, stream>>>(ws1, ws2, 4, 0);  // 64  -> 8
    sig_tree_s<<<1, 256, 0, stream>>>(ws2, out, 4, 1);  // 8   -> 1
}

// Round 8
// 93.046 us; speedup vs baseline: 2.3087x; 1.0494x over previous
//
#include <hip/hip_runtime.h>

#define DIM 6
#define NSEG 65535
#define CH 64             // segments per chunk (per wave)
#define WPB 4             // waves (=chunks) per fold block
#define NBLK 256          // fold blocks; NBLK*WPB*CH >= NSEG -> 256 partials

// Padded partial-signature layout (per chunk), stride in floats.
// 16B-aligned sections: L1@0(6), L2@8(36), L3@48(216), L4@264(1296)
#define PSTRIDE 1568
#define PL1 0
#define PL2 8
#define PL3 48
#define PL4 264
#define NGRP 259          // 1 + 6 + 36 + 216 output groups of 6

// ---------------- Chen pair-combine helpers (padded layout) -----------------
// Group g: 0 -> L1; 1..6 -> L2 row a; 7..42 -> L3 row ab; 43..258 -> L4 row abc.
// A,B are padded 1568-float signatures (global or LDS via generic pointer).
__device__ __forceinline__ void chen_vals(const float* __restrict__ A,
                                          const float* __restrict__ B,
                                          int g, float* v) {
    if (g == 0) {
#pragma unroll
        for (int d = 0; d < 6; ++d) v[d] = A[PL1 + d] + B[PL1 + d];
    } else if (g < 7) {
        int a = g - 1;
        float a1 = A[PL1 + a];
        const float* Ar = A + PL2 + a * 6;
        const float* Br = B + PL2 + a * 6;
#pragma unroll
        for (int d = 0; d < 6; ++d) v[d] = Ar[d] + Br[d] + a1 * B[PL1 + d];
    } else if (g < 43) {
        int ab = g - 7, a = ab / 6, b = ab - a * 6;
        float a2 = A[PL2 + ab], a1 = A[PL1 + a];
        const float* Ar = A + PL3 + ab * 6;
        const float* Br = B + PL3 + ab * 6;
        const float* B2r = B + PL2 + b * 6;
#pragma unroll
        for (int d = 0; d < 6; ++d)
            v[d] = Ar[d] + Br[d] + a2 * B[PL1 + d] + a1 * B2r[d];
    } else {
        int abc = g - 43, ab = abc / 6, cc = abc - ab * 6, a = abc / 36,
            bc = abc - a * 36;
        float a3 = A[PL3 + abc], a2 = A[PL2 + ab], a1 = A[PL1 + a];
        const float* Ar = A + PL4 + abc * 6;
        const float* Br = B + PL4 + abc * 6;
        const float* B2r = B + PL2 + cc * 6;
        const float* B3r = B + PL3 + bc * 6;
#pragma unroll
        for (int d = 0; d < 6; ++d)
            v[d] = Ar[d] + Br[d] + a3 * B[PL1 + d] + a2 * B2r[d] + a1 * B3r[d];
    }
}

__device__ __forceinline__ int grp_off_padded(int g) {
    if (g == 0) return PL1;
    if (g < 7) return PL2 + (g - 1) * 6;
    if (g < 43) return PL3 + (g - 7) * 6;
    return PL4 + (g - 43) * 6;
}
__device__ __forceinline__ int grp_off_flat(int g) {
    if (g == 0) return 0;
    if (g < 7) return 6 + (g - 1) * 6;
    if (g < 43) return 42 + (g - 7) * 6;
    return 258 + (g - 43) * 6;
}

__device__ __forceinline__ void write_final(float* out, int flat_out, int g,
                                            const float* v, int blk) {
    if (flat_out) {
        int off = grp_off_flat(g);
#pragma unroll
        for (int d = 0; d < 6; ++d) out[off + d] = v[d];
    } else {
        float* O = out + (size_t)blk * PSTRIDE;
        int off = grp_off_padded(g);
#pragma unroll
        for (int d = 0; d < 6; ++d) O[off + d] = v[d];
    }
}

// ---------------- Kernel 1: 4 waves/block, one 64-seg chunk per wave --------
// Each wave runs the proven register-resident Chen fold over CH=64 segments,
// writes its partial to LDS, then the block Chen-combines 4 partials -> 1
// (radix-4, 2 levels) and writes ONE global partial.  256 blocks -> 256
// partials (tree input 1.6 MB).  [Verified best config: 92.0 us round 4.]
__global__ __launch_bounds__(256) void sig_fold4(const float* __restrict__ x,
                                                 float* __restrict__ part) {
    __shared__ __align__(16) float dxs[WPB * CH * 8];  // 8 KB
    __shared__ __align__(16) float P[WPB * PSTRIDE];   // 25.1 KB per-wave partials
    __shared__ __align__(16) float Q[2 * PSTRIDE];     // 12.5 KB combine buffer
    const int t = threadIdx.x;
    const int w = t >> 6;                 // wave id 0..3
    const int lane = t & 63;
    const int c = blockIdx.x * WPB + w;   // chunk id 0..1023
    const int j0 = c * CH;
    const int cnt = min(CH, NSEG - j0);   // 64, or 63 for the last chunk

    float* dxw = dxs + w * (CH * 8);
    for (int f = lane; f < CH * 8; f += 64) dxw[f] = 0.f;
    __syncthreads();
    const float* xb = x + (size_t)j0 * DIM;
    for (int f = lane; f < cnt * DIM; f += 64) {
        int j = f / 6, k = f - j * 6;
        dxw[j * 8 + k] = xb[f + 6] - xb[f];
    }
    __syncthreads();

    const int ab = (lane < 36) ? lane : 35;
    const int a = ab / 6, b = ab - a * 6;
    const float* dxap = dxw + a;          // lane-varying LDS bases
    const float* dxbp = dxw + b;

    float r4[36], r3[6], r2 = 0.f, s1 = 0.f;
#pragma unroll
    for (int i = 0; i < 36; ++i) r4[i] = 0.f;
#pragma unroll
    for (int i = 0; i < 6; ++i) r3[i] = 0.f;

#pragma unroll 2
    for (int j = 0; j < CH; ++j) {
        const float4 q0 = *(const float4*)(dxw + j * 8);
        const float2 q1 = *(const float2*)(dxw + j * 8 + 4);
        const float dxv[6] = {q0.x, q0.y, q0.z, q0.w, q1.x, q1.y}; // const-idx only
        const float dxa = dxap[j * 8];    // ds_read lane-addressed
        const float dxb = dxbp[j * 8];

        // t2 = S2 + dx_b*(S1/3 + dx_a/12)            (old S2, S1)
        float t2 = fmaf(dxb, fmaf(dxa, (1.f / 12.f), s1 * (1.f / 3.f)), r2);
        float t2h = 0.5f * t2;                        // *0.5 is exact
        // S4[cd] += (S3[c] + t2*0.5*dx[c]) * dx[d]   (old S3)
        float wv[6];
#pragma unroll
        for (int cc = 0; cc < 6; ++cc) wv[cc] = fmaf(t2h, dxv[cc], r3[cc]);
#pragma unroll
        for (int cc = 0; cc < 6; ++cc)
#pragma unroll
            for (int d = 0; d < 6; ++d)
                r4[cc * 6 + d] = fmaf(wv[cc], dxv[d], r4[cc * 6 + d]);
        // S3[c] += (S2 + t3*0.5*dx_b) * dx[c],  t3 = S1 + dx_a/3
        float t3 = fmaf(dxa, (1.f / 3.f), s1);
        float v = fmaf(0.5f * t3, dxb, r2);
#pragma unroll
        for (int cc = 0; cc < 6; ++cc) r3[cc] = fmaf(v, dxv[cc], r3[cc]);
        // S2 += (S1 + 0.5*dx_a) * dx_b ; S1 += dx_a
        r2 = fmaf(fmaf(0.5f, dxa, s1), dxb, r2);
        s1 += dxa;
    }

    // write wave partial into LDS (padded layout)
    if (lane < 36) {
        float* Pw = P + w * PSTRIDE;
        if (a == b) Pw[PL1 + a] = s1;
        Pw[PL2 + ab] = r2;
        float* p3 = Pw + PL3 + ab * 6;
        *(float2*)(p3 + 0) = make_float2(r3[0], r3[1]);
        *(float2*)(p3 + 2) = make_float2(r3[2], r3[3]);
        *(float2*)(p3 + 4) = make_float2(r3[4], r3[5]);
        float* p4 = Pw + PL4 + ab * 36;
#pragma unroll
        for (int i = 0; i < 9; ++i)
            *(float4*)(p4 + 4 * i) =
                make_float4(r4[4 * i], r4[4 * i + 1], r4[4 * i + 2], r4[4 * i + 3]);
    }
    __syncthreads();

    // level 1: (P0,P1)->Q0, (P2,P3)->Q1   (path order preserved)
    for (int idx = t; idx < 2 * NGRP; idx += 256) {
        int p = idx / NGRP, g = idx - p * NGRP;
        float v[6];
        chen_vals(P + (2 * p) * PSTRIDE, P + (2 * p + 1) * PSTRIDE, g, v);
        float* o = Q + p * PSTRIDE + grp_off_padded(g);
#pragma unroll
        for (int d = 0; d < 6; ++d) o[d] = v[d];
    }
    __syncthreads();

    // level 2: Q0*Q1 -> global partial for this block
    for (int idx = t; idx < NGRP; idx += 256) {
        float v[6];
        chen_vals(Q, Q + PSTRIDE, idx, v);
        float* O = part + (size_t)blockIdx.x * PSTRIDE + grp_off_padded(idx);
#pragma unroll
        for (int d = 0; d < 6; ++d) O[d] = v[d];
    }
}

// ---------------- Kernel 2: staged radix-(2*np0) in-block Chen tree ---------
// Stages gs = 2*np0 input partials into LDS with COALESCED float4 streams
// (replacing the latency-bound scattered global gather), then runs all Chen
// levels out of LDS.  np0 in {4, 2}.  LDS = 75.3 KB.
__global__ __launch_bounds__(256) void sig_tree_s(const float* __restrict__ in,
                                                  float* __restrict__ out,
                                                  int np0, int flat_out) {
    __shared__ __align__(16) float LIN[8 * PSTRIDE];  // 50.2 KB staged inputs
    __shared__ __align__(16) float W[4 * PSTRIDE];    // 25.1 KB ping-pong
    const int t = threadIdx.x;
    const int gs = np0 * 2;
    const float* gbase = in + (size_t)blockIdx.x * gs * PSTRIDE;

    // coalesced staging: gs*PSTRIDE floats as float4 streams
    const int nvec = gs * (PSTRIDE / 4);
    for (int f = t; f < nvec; f += 256)
        *(float4*)(LIN + 4 * f) = *(const float4*)(gbase + 4 * f);
    __syncthreads();

    float* cur = LIN;
    float* nxt = W;
    for (int np = np0;; np >>= 1) {
        for (int idx = t; idx < np * NGRP; idx += 256) {
            int p = idx / NGRP, g = idx - p * NGRP;
            float v[6];
            chen_vals(cur + (2 * p) * PSTRIDE, cur + (2 * p + 1) * PSTRIDE, g, v);
            if (np == 1) {
                write_final(out, flat_out, g, v, blockIdx.x);
            } else {
                float* o = nxt + p * PSTRIDE + grp_off_padded(g);
#pragma unroll
                for (int d = 0; d < 6; ++d) o[d] = v[d];
            }
        }
        if (np == 1) break;
        __syncthreads();
        float* tmp = cur; cur = nxt; nxt = tmp;
    }
}

// ---------------------------------------------------------------------------
extern "C" void kernel_launch(void* const* d_in, const int* in_sizes, int n_in,
                              void* d_out, int out_size, void* d_ws, size_t ws_size,
                              hipStream_t stream) {
    const float* x = (const float*)d_in[0];
    float* out = (float*)d_out;
    float* ws0 = (float*)d_ws;                          // 256 padded partials
    float* ws1 = ws0 + (size_t)NBLK * PSTRIDE;          // 32 padded partials
    float* ws2 = ws1 + (size_t)32 * PSTRIDE;            // 4 padded partials

    sig_fold4<<<NBLK, 256, 0, stream>>>(x, ws0);        // 65535 segs -> 256
    sig_tree_s<<<32, 256, 0, stream>>>(ws0, ws1, 4, 0); // 256 -> 32
    sig_tree_s<<<4, 256, 0, stream>>>(ws1, ws2, 4, 0);  // 32  -> 4
    sig_tree_s<<<1, 256, 0, stream>>>(ws2, out, 2, 1);  // 4   -> 1
}